// Round 2
// baseline (548.620 us; speedup 1.0000x reference)
//
#include <hip/hip_runtime.h>

using bf16   = __bf16;
using bf16x8 = __attribute__((ext_vector_type(8))) bf16;
using bf16x4 = __attribute__((ext_vector_type(4))) bf16;
using f32x4  = __attribute__((ext_vector_type(4))) float;

#define DEV static __device__ __forceinline__

DEV bf16x4 lo4(bf16x8 v){ return __builtin_shufflevector(v, v, 0,1,2,3); }
DEV bf16x4 hi4(bf16x8 v){ return __builtin_shufflevector(v, v, 4,5,6,7); }
DEV bf16x8 cat8(bf16x4 a, bf16x4 b){ return __builtin_shufflevector(a, b, 0,1,2,3,4,5,6,7); }

DEV void MFMA16(bf16x8 a, bf16x8 b, f32x4& c){
  c = __builtin_amdgcn_mfma_f32_16x16x32_bf16(a, b, c, 0, 0, 0);
}

// ---- transpose-cast: out[c][r] = bf16(in[r][c]); R,C multiples of 32 ----
__global__ __launch_bounds__(256) void tcast(const float* __restrict__ in, bf16* __restrict__ out,
                                             int R, int C)
{
  __shared__ float t[32][33];
  const int c0 = blockIdx.x*32, r0 = blockIdx.y*32;
  const int tx = threadIdx.x & 31, ty = threadIdx.x >> 5;
  #pragma unroll
  for (int i = ty; i < 32; i += 8) t[i][tx] = in[(size_t)(r0+i)*C + c0+tx];
  __syncthreads();
  #pragma unroll
  for (int i = ty; i < 32; i += 8) out[(size_t)(c0+i)*R + r0+tx] = (bf16)t[tx][i];
}

__global__ void cast_bf16(const float* __restrict__ in, bf16* __restrict__ out, int n){
  int i = blockIdx.x*256 + threadIdx.x;
  if (i < n) out[i] = (bf16)in[i];
}

// ---- LayerNorm: one block per row of 1024, fp32 in -> bf16 out ----
__global__ __launch_bounds__(256) void ln_kernel(const float* __restrict__ x,
    const float* __restrict__ gw, const float* __restrict__ bw, bf16* __restrict__ y)
{
  const int row = blockIdx.x;
  const float4 v = ((const float4*)(x + (size_t)row*1024))[threadIdx.x];
  float s  = v.x+v.y+v.z+v.w;
  float s2 = v.x*v.x+v.y*v.y+v.z*v.z+v.w*v.w;
  #pragma unroll
  for (int off=32; off>=1; off>>=1){ s += __shfl_down(s,off); s2 += __shfl_down(s2,off); }
  __shared__ float red[2][4];
  const int wid = threadIdx.x>>6, lane = threadIdx.x&63;
  if (lane==0){ red[0][wid]=s; red[1][wid]=s2; }
  __syncthreads();
  s  = red[0][0]+red[0][1]+red[0][2]+red[0][3];
  s2 = red[1][0]+red[1][1]+red[1][2]+red[1][3];
  const float m  = s*(1.f/1024.f);
  const float rs = rsqrtf(s2*(1.f/1024.f) - m*m + 1e-5f);
  const float4 gv = ((const float4*)gw)[threadIdx.x];
  const float4 bv = ((const float4*)bw)[threadIdx.x];
  bf16* yr = y + (size_t)row*1024 + threadIdx.x*4;
  yr[0] = (bf16)((v.x-m)*rs*gv.x + bv.x);
  yr[1] = (bf16)((v.y-m)*rs*gv.y + bv.y);
  yr[2] = (bf16)((v.z-m)*rs*gv.z + bv.z);
  yr[3] = (bf16)((v.w-m)*rs*gv.w + bv.w);
}

// ---- GEMM: out = epilogue(A[M][K] @ Bt[N][K]^T); 128x128 tile, BK=32 ----
// LDS stores each 32-k chunk permuted (k=16h+4g+e -> k'=8g+4h+e) so an MFMA
// fragment is one contiguous 16B read at elem offset 8*(lane>>4).
// Each thread stages TWO rows (srow, srow+64) of both A and B: 256 thr x 2 x 8
// elems = full 128x32 tile.
template<int MODE>
__global__ __launch_bounds__(256) void gemm_bt(
    const bf16* __restrict__ A, const bf16* __restrict__ Bt,
    const float* __restrict__ bias, const float* resid,
    void* outp, int M, int N, int K)
{
  __shared__ __align__(16) bf16 As[128*56];
  __shared__ __align__(16) bf16 Bs[128*56];
  const int tid = threadIdx.x;
  const int lane = tid & 63, wid = tid >> 6;
  const int l15 = lane & 15, lh = lane >> 4;
  const int wm = wid >> 1, wn = wid & 1;
  const size_t m0 = (size_t)blockIdx.y * 128, n0 = (size_t)blockIdx.x * 128;
  f32x4 acc[4][4];
  #pragma unroll
  for (int i=0;i<4;++i)
    #pragma unroll
    for (int j=0;j<4;++j) acc[i][j] = (f32x4){0.f,0.f,0.f,0.f};

  const int srow = tid >> 2, c32 = tid & 3;
  const int d1 = 8*((2*c32)&3)   + 4*(c32>>1);
  const int d2 = 8*((2*c32+1)&3) + 4*(c32>>1);
  size_t ar0 = m0 + srow;      if (ar0 >= (size_t)M) ar0 = (size_t)M - 1;
  size_t ar1 = m0 + srow + 64; if (ar1 >= (size_t)M) ar1 = (size_t)M - 1;
  const bf16* ap0 = A  + ar0*(size_t)K + c32*8;
  const bf16* ap1 = A  + ar1*(size_t)K + c32*8;
  const bf16* bp0 = Bt + (n0 + srow)*(size_t)K + c32*8;
  const bf16* bp1 = Bt + (n0 + srow + 64)*(size_t)K + c32*8;

  for (int k0 = 0; k0 < K; k0 += 32) {
    bf16x8 a0 = *(const bf16x8*)(ap0 + k0);
    bf16x8 a1 = *(const bf16x8*)(ap1 + k0);
    bf16x8 b0 = *(const bf16x8*)(bp0 + k0);
    bf16x8 b1 = *(const bf16x8*)(bp1 + k0);
    __syncthreads();
    *(bf16x4*)&As[ srow     *56 + d1] = lo4(a0);
    *(bf16x4*)&As[ srow     *56 + d2] = hi4(a0);
    *(bf16x4*)&As[(srow+64) *56 + d1] = lo4(a1);
    *(bf16x4*)&As[(srow+64) *56 + d2] = hi4(a1);
    *(bf16x4*)&Bs[ srow     *56 + d1] = lo4(b0);
    *(bf16x4*)&Bs[ srow     *56 + d2] = hi4(b0);
    *(bf16x4*)&Bs[(srow+64) *56 + d1] = lo4(b1);
    *(bf16x4*)&Bs[(srow+64) *56 + d2] = hi4(b1);
    __syncthreads();
    bf16x8 af[4], bfr[4];
    #pragma unroll
    for (int i=0;i<4;++i){
      af[i]  = *(const bf16x8*)&As[(wm*64 + i*16 + l15)*56 + 8*lh];
      bfr[i] = *(const bf16x8*)&Bs[(wn*64 + i*16 + l15)*56 + 8*lh];
    }
    #pragma unroll
    for (int mi=0;mi<4;++mi)
      #pragma unroll
      for (int ni=0;ni<4;++ni)
        MFMA16(af[mi], bfr[ni], acc[mi][ni]);
  }
  #pragma unroll
  for (int mi=0;mi<4;++mi){
    #pragma unroll
    for (int r=0;r<4;++r){
      size_t row = m0 + wm*64 + mi*16 + 4*lh + r;
      if (row < (size_t)M) {
        #pragma unroll
        for (int ni=0;ni<4;++ni){
          size_t col = n0 + wn*64 + ni*16 + l15;
          float v = acc[mi][ni][r];
          if (MODE==0) ((bf16*)outp)[row*(size_t)N + col] = (bf16)v;
          else if (MODE==1) ((float*)outp)[row*(size_t)N + col] = v + bias[col] + resid[row*(size_t)N + col];
          else { v += bias[col];
                 ((bf16*)outp)[row*(size_t)N + col] =
                     (bf16)(0.5f*v*(1.0f + erff(v*0.70710678f))); }
        }
      }
    }
  }
}

// ---- V rearrange for SA: vt[bh][d][s] = qkv[b*2048+s][2048 + h*64 + d] ----
__global__ __launch_bounds__(256) void vtsa_kernel(const bf16* __restrict__ qkv, bf16* __restrict__ vt)
{
  __shared__ bf16 t[32][33];
  const int b = blockIdx.z >> 4, h = blockIdx.z & 15;
  const int s0 = blockIdx.x*32, d0 = blockIdx.y*32;
  const int tx = threadIdx.x & 31, ty = threadIdx.x >> 5;
  #pragma unroll
  for (int i = ty; i < 32; i += 8)
    t[i][tx] = qkv[(size_t)(b*2048 + s0+i)*3072 + 2048 + h*64 + d0 + tx];
  __syncthreads();
  #pragma unroll
  for (int i = ty; i < 32; i += 8)
    vt[((size_t)blockIdx.z*64 + d0+i)*2048 + s0 + tx] = t[tx][i];
}

// ---- CA KV rearrange (pad 77 -> 128, zero fill) ----
__global__ __launch_bounds__(256) void kvca_re(const bf16* __restrict__ kvca,
    bf16* __restrict__ kpad, bf16* __restrict__ vtca)
{
  int idx = blockIdx.x*256 + threadIdx.x;           // over 2*16*128*64 = 262144
  if (idx >= 2*16*128*64) return;
  int d = idx & 63, s = (idx>>6) & 127, h = (idx>>13) & 15, b = idx>>17;
  bf16 kv = (bf16)0.f, vv = (bf16)0.f;
  if (s < 77) {
    kv = kvca[(size_t)(b*77+s)*2048 + h*64 + d];
    vv = kvca[(size_t)(b*77+s)*2048 + 1024 + h*64 + d];
  }
  kpad[idx] = kv;                                   // [b][h][s][d]
  vtca[(((size_t)(b*16+h)*64 + d)<<7) + s] = vv;    // [b][h][d][s], stride 128
}

// ---- Flash attention: 64 q-rows/block, 4 waves x 16 rows, SBLK=64, DH=64 ----
__global__ __launch_bounds__(256) void flash_attn(
    const bf16* __restrict__ qb, long q_bstride, long qstride,
    const bf16* __restrict__ kb0, long k_bstride, long k_hstride, long kstride,
    const bf16* __restrict__ vtb, long vt_bhstride, long vtstride,
    bf16* __restrict__ out, int skv, int causal)
{
  __shared__ __align__(16) bf16 Ks[64*72];
  __shared__ __align__(16) bf16 Vs[64*72];
  __shared__ __align__(16) bf16 Ps[4][16*72];
  const int tid = threadIdx.x;
  const int w = tid >> 6, lane = tid & 63, l15 = lane & 15, lh = lane >> 4;
  const int bh = blockIdx.y, b = bh >> 4, h = bh & 15;
  const int q0 = blockIdx.x * 64;
  const int nkb = causal ? (q0 >> 6) + 1 : ((skv + 63) >> 6);

  const bf16* qrow = qb + (size_t)b*q_bstride + h*64 + (size_t)(q0 + w*16 + l15)*qstride;
  bf16x8 qf0 = cat8(*(const bf16x4*)(qrow      + 4*lh), *(const bf16x4*)(qrow + 16 + 4*lh));
  bf16x8 qf1 = cat8(*(const bf16x4*)(qrow + 32 + 4*lh), *(const bf16x4*)(qrow + 48 + 4*lh));
  const bf16* kbase = kb0 + (size_t)b*k_bstride + (size_t)h*k_hstride;
  const bf16* vbase = vtb + (size_t)bh*vt_bhstride;

  f32x4 o[4];
  #pragma unroll
  for (int i=0;i<4;++i) o[i] = (f32x4){0.f,0.f,0.f,0.f};
  float mr[4] = {-1e30f,-1e30f,-1e30f,-1e30f};
  float lr[4] = {0.f,0.f,0.f,0.f};

  for (int kb = 0; kb < nkb; ++kb) {
    __syncthreads();
    #pragma unroll
    for (int i = 0; i < 2; ++i) {
      int chunk = tid + i*256;
      int s = chunk >> 3, c0 = chunk & 7;
      int c32 = c0 & 3, ch32 = c0 >> 2;
      int p1 = 32*ch32 + 8*((2*c32)&3)   + 4*(c32>>1);
      int p2 = 32*ch32 + 8*((2*c32+1)&3) + 4*(c32>>1);
      bf16x8 kv = *(const bf16x8*)(kbase + (size_t)(kb*64 + s)*kstride + c0*8);
      *(bf16x4*)&Ks[s*72 + p1] = lo4(kv);
      *(bf16x4*)&Ks[s*72 + p2] = hi4(kv);
      bf16x8 vv = *(const bf16x8*)(vbase + (size_t)s*vtstride + kb*64 + c0*8);
      *(bf16x4*)&Vs[s*72 + p1] = lo4(vv);
      *(bf16x4*)&Vs[s*72 + p2] = hi4(vv);
    }
    __syncthreads();

    f32x4 sf[4];
    #pragma unroll
    for (int ni = 0; ni < 4; ++ni) {
      bf16x8 kf0 = *(const bf16x8*)&Ks[(ni*16 + l15)*72 + 8*lh];
      bf16x8 kf1 = *(const bf16x8*)&Ks[(ni*16 + l15)*72 + 32 + 8*lh];
      f32x4 z = (f32x4){0.f,0.f,0.f,0.f};
      MFMA16(qf0, kf0, z);
      MFMA16(qf1, kf1, z);
      sf[ni] = z;
    }
    float mnew[4];
    #pragma unroll
    for (int r=0;r<4;++r) mnew[r] = mr[r];
    #pragma unroll
    for (int ni=0;ni<4;++ni){
      int col = kb*64 + ni*16 + l15;
      #pragma unroll
      for (int r=0;r<4;++r){
        int rowg = q0 + w*16 + 4*lh + r;
        float v = sf[ni][r] * 0.125f;
        if (col >= skv || (causal && col > rowg)) v = -1e30f;
        sf[ni][r] = v;
        mnew[r] = fmaxf(mnew[r], v);
      }
    }
    #pragma unroll
    for (int off=1; off<16; off<<=1)
      #pragma unroll
      for (int r=0;r<4;++r) mnew[r] = fmaxf(mnew[r], __shfl_xor(mnew[r], off));
    float alpha[4], rsum[4];
    #pragma unroll
    for (int r=0;r<4;++r){ alpha[r] = __expf(mr[r]-mnew[r]); mr[r] = mnew[r]; rsum[r] = 0.f; }
    #pragma unroll
    for (int ni=0;ni<4;++ni){
      int sloc = 32*(ni>>1) + 8*(l15>>2) + 4*(ni&1) + (l15&3);
      #pragma unroll
      for (int r=0;r<4;++r){
        float p = __expf(sf[ni][r] - mnew[r]);
        rsum[r] += p;
        Ps[w][(4*lh + r)*72 + sloc] = (bf16)p;
      }
    }
    #pragma unroll
    for (int off=1; off<16; off<<=1)
      #pragma unroll
      for (int r=0;r<4;++r) rsum[r] += __shfl_xor(rsum[r], off);
    #pragma unroll
    for (int r=0;r<4;++r) lr[r] = lr[r]*alpha[r] + rsum[r];
    #pragma unroll
    for (int nd=0;nd<4;++nd)
      #pragma unroll
      for (int r=0;r<4;++r) o[nd][r] *= alpha[r];

    bf16x8 pa0 = *(const bf16x8*)&Ps[w][l15*72 + 8*lh];
    bf16x8 pa1 = *(const bf16x8*)&Ps[w][l15*72 + 32 + 8*lh];
    #pragma unroll
    for (int nd=0;nd<4;++nd){
      bf16x8 vf0 = *(const bf16x8*)&Vs[(nd*16+l15)*72 + 8*lh];
      bf16x8 vf1 = *(const bf16x8*)&Vs[(nd*16+l15)*72 + 32 + 8*lh];
      MFMA16(pa0, vf0, o[nd]);
      MFMA16(pa1, vf1, o[nd]);
    }
  }
  #pragma unroll
  for (int nd=0;nd<4;++nd)
    #pragma unroll
    for (int r=0;r<4;++r){
      int rowg = q0 + w*16 + 4*lh + r;
      out[(size_t)(b*2048 + rowg)*1024 + h*64 + nd*16 + l15] =
          (bf16)(o[nd][r] / lr[r]);
    }
}

// ---- host ----
struct Bump { char* base; size_t off;
  void* get(size_t bytes){ void* p = base + off; off += (bytes + 255) & ~(size_t)255; return p; } };

extern "C" void kernel_launch(void* const* d_in, const int* in_sizes, int n_in,
                              void* d_out, int out_size, void* d_ws, size_t ws_size,
                              hipStream_t stream)
{
  const float* x        = (const float*)d_in[0];
  const float* cond     = (const float*)d_in[1];
  const float* Wqkv     = (const float*)d_in[2];
  const float* Wproj_sa = (const float*)d_in[3];
  const float* bproj_sa = (const float*)d_in[4];
  const float* g1       = (const float*)d_in[5];
  const float* b1       = (const float*)d_in[6];
  const float* Wq_ca    = (const float*)d_in[7];
  const float* Wkv_ca   = (const float*)d_in[8];
  const float* Wproj_ca = (const float*)d_in[9];
  const float* bproj_ca = (const float*)d_in[10];
  const float* g2       = (const float*)d_in[11];
  const float* b2       = (const float*)d_in[12];
  const float* Wff1     = (const float*)d_in[13];
  const float* bff1     = (const float*)d_in[14];
  const float* Wff2     = (const float*)d_in[15];
  const float* bff2     = (const float*)d_in[16];
  const float* g3       = (const float*)d_in[17];
  const float* b3       = (const float*)d_in[18];

  Bump bump{(char*)d_ws, 0};
  bf16* wqkvT    = (bf16*)bump.get((size_t)3072*1024*2);
  bf16* wprojSaT = (bf16*)bump.get((size_t)1024*1024*2);
  bf16* wqCaT    = (bf16*)bump.get((size_t)1024*1024*2);
  bf16* wkvCaT   = (bf16*)bump.get((size_t)2048*768*2);
  bf16* wprojCaT = (bf16*)bump.get((size_t)1024*1024*2);
  bf16* wff1T    = (bf16*)bump.get((size_t)4096*1024*2);
  bf16* wff2T    = (bf16*)bump.get((size_t)1024*4096*2);
  bf16* condb    = (bf16*)bump.get((size_t)154*768*2);
  bf16* xn       = (bf16*)bump.get((size_t)4096*1024*2);
  bf16* qkv      = (bf16*)bump.get((size_t)4096*3072*2);   // 25165824 B
  bf16* vt_sa    = (bf16*)bump.get((size_t)2*16*64*2048*2);//  8388608 B (directly follows qkv)
  bf16* attn     = (bf16*)bump.get((size_t)4096*1024*2);
  bf16* kvca     = (bf16*)bump.get((size_t)154*2048*2);
  bf16* kpad     = (bf16*)bump.get((size_t)2*16*128*64*2);
  bf16* vtca     = (bf16*)bump.get((size_t)2*16*64*128*2);
  bf16* h1   = qkv;             // FF hidden: qkv+vt_sa dead by FF1 (needs 32 MiB exactly)
  bf16* qca  = vt_sa;           // CA query: vt_sa dead after SA flash
  float* x1  = (float*)d_out;   // residual stream lives in d_out

  tcast<<<dim3(96,32),  256, 0, stream>>>(Wqkv,     wqkvT,    1024, 3072);
  tcast<<<dim3(32,32),  256, 0, stream>>>(Wproj_sa, wprojSaT, 1024, 1024);
  tcast<<<dim3(32,32),  256, 0, stream>>>(Wq_ca,    wqCaT,    1024, 1024);
  tcast<<<dim3(64,24),  256, 0, stream>>>(Wkv_ca,   wkvCaT,    768, 2048);
  tcast<<<dim3(32,32),  256, 0, stream>>>(Wproj_ca, wprojCaT, 1024, 1024);
  tcast<<<dim3(128,32), 256, 0, stream>>>(Wff1,     wff1T,    1024, 4096);
  tcast<<<dim3(32,128), 256, 0, stream>>>(Wff2,     wff2T,    4096, 1024);
  cast_bf16<<<dim3(462), 256, 0, stream>>>(cond, condb, 118272);

  // self-attention
  ln_kernel<<<dim3(4096), 256, 0, stream>>>(x, g1, b1, xn);
  gemm_bt<0><<<dim3(24,32), 256, 0, stream>>>(xn, wqkvT, nullptr, nullptr, qkv, 4096, 3072, 1024);
  vtsa_kernel<<<dim3(64,2,32), 256, 0, stream>>>(qkv, vt_sa);
  flash_attn<<<dim3(32,32), 256, 0, stream>>>(
      qkv,        (long)2048*3072, 3072,
      qkv + 1024, (long)2048*3072, 64, 3072,
      vt_sa,      (long)64*2048, 2048,
      attn, 2048, 1);
  gemm_bt<1><<<dim3(8,32), 256, 0, stream>>>(attn, wprojSaT, bproj_sa, x, x1, 4096, 1024, 1024);

  // cross-attention
  ln_kernel<<<dim3(4096), 256, 0, stream>>>(x1, g2, b2, xn);
  gemm_bt<0><<<dim3(8,32), 256, 0, stream>>>(xn, wqCaT, nullptr, nullptr, qca, 4096, 1024, 1024);
  gemm_bt<0><<<dim3(16,2), 256, 0, stream>>>(condb, wkvCaT, nullptr, nullptr, kvca, 154, 2048, 768);
  kvca_re<<<dim3(1024), 256, 0, stream>>>(kvca, kpad, vtca);
  flash_attn<<<dim3(32,32), 256, 0, stream>>>(
      qca,  (long)2048*1024, 1024,
      kpad, (long)16*128*64, (long)128*64, 64,
      vtca, (long)64*128, 128,
      attn, 77, 0);
  gemm_bt<1><<<dim3(8,32), 256, 0, stream>>>(attn, wprojCaT, bproj_ca, x1, x1, 4096, 1024, 1024);

  // FFN
  ln_kernel<<<dim3(4096), 256, 0, stream>>>(x1, g3, b3, xn);
  gemm_bt<2><<<dim3(32,32), 256, 0, stream>>>(xn, wff1T, bff1, nullptr, h1, 4096, 4096, 1024);
  gemm_bt<1><<<dim3(8,32), 256, 0, stream>>>(h1, wff2T, bff2, x1, d_out, 4096, 1024, 4096);

  (void)in_sizes; (void)n_in; (void)out_size; (void)ws_size;
}

// Round 3
// 487.515 us; speedup vs baseline: 1.1253x; 1.1253x over previous
//
#include <hip/hip_runtime.h>

using bf16   = __bf16;
using bf16x8 = __attribute__((ext_vector_type(8))) bf16;
using f32x4  = __attribute__((ext_vector_type(4))) float;

#define DEV static __device__ __forceinline__

DEV void MFMA16(bf16x8 a, bf16x8 b, f32x4& c){
  c = __builtin_amdgcn_mfma_f32_16x16x32_bf16(a, b, c, 0, 0, 0);
}

// async global->LDS DMA, 16B per lane; lds dest must be wave-uniform base
DEV void gload16(const bf16* g, bf16* lds){
  __builtin_amdgcn_global_load_lds(
      (const __attribute__((address_space(1))) void*)g,
      (__attribute__((address_space(3))) void*)lds, 16, 0, 0);
}

// ---- transpose-cast: out[c][r] = bf16(in[r][c]); R,C multiples of 32 ----
__global__ __launch_bounds__(256) void tcast(const float* __restrict__ in, bf16* __restrict__ out,
                                             int R, int C)
{
  __shared__ float t[32][33];
  const int c0 = blockIdx.x*32, r0 = blockIdx.y*32;
  const int tx = threadIdx.x & 31, ty = threadIdx.x >> 5;
  #pragma unroll
  for (int i = ty; i < 32; i += 8) t[i][tx] = in[(size_t)(r0+i)*C + c0+tx];
  __syncthreads();
  #pragma unroll
  for (int i = ty; i < 32; i += 8) out[(size_t)(c0+i)*R + r0+tx] = (bf16)t[tx][i];
}

__global__ void cast_bf16(const float* __restrict__ in, bf16* __restrict__ out, int n){
  int i = blockIdx.x*256 + threadIdx.x;
  if (i < n) out[i] = (bf16)in[i];
}

// ---- LayerNorm: one block per row of 1024, fp32 in -> bf16 out ----
__global__ __launch_bounds__(256) void ln_kernel(const float* __restrict__ x,
    const float* __restrict__ gw, const float* __restrict__ bw, bf16* __restrict__ y)
{
  const int row = blockIdx.x;
  const float4 v = ((const float4*)(x + (size_t)row*1024))[threadIdx.x];
  float s  = v.x+v.y+v.z+v.w;
  float s2 = v.x*v.x+v.y*v.y+v.z*v.z+v.w*v.w;
  #pragma unroll
  for (int off=32; off>=1; off>>=1){ s += __shfl_down(s,off); s2 += __shfl_down(s2,off); }
  __shared__ float red[2][4];
  const int wid = threadIdx.x>>6, lane = threadIdx.x&63;
  if (lane==0){ red[0][wid]=s; red[1][wid]=s2; }
  __syncthreads();
  s  = red[0][0]+red[0][1]+red[0][2]+red[0][3];
  s2 = red[1][0]+red[1][1]+red[1][2]+red[1][3];
  const float m  = s*(1.f/1024.f);
  const float rs = rsqrtf(s2*(1.f/1024.f) - m*m + 1e-5f);
  const float4 gv = ((const float4*)gw)[threadIdx.x];
  const float4 bv = ((const float4*)bw)[threadIdx.x];
  bf16* yr = y + (size_t)row*1024 + threadIdx.x*4;
  yr[0] = (bf16)((v.x-m)*rs*gv.x + bv.x);
  yr[1] = (bf16)((v.y-m)*rs*gv.y + bv.y);
  yr[2] = (bf16)((v.z-m)*rs*gv.z + bv.z);
  yr[3] = (bf16)((v.w-m)*rs*gv.w + bv.w);
}

// ---- GEMM (m97 structure): out = epilogue(A[M][K] @ Bt[N][K]^T) ----
// 128x128 tile, BK=64, linear LDS [128][64], global_load_lds width-16 staging,
// 2 barriers per K-step, 32 MFMA/wave/K-step. Natural contiguous fragments:
// lane reads [row][32*kk + 8*(lane>>4)] (same k-labeling for A and B).
template<int MODE>
__global__ __launch_bounds__(256) void gemm_bt(
    const bf16* __restrict__ A, const bf16* __restrict__ Bt,
    const float* __restrict__ bias, const float* resid,
    void* outp, int M, int N, int K)
{
  __shared__ __align__(16) bf16 As[128*64];
  __shared__ __align__(16) bf16 Bs[128*64];
  const int tid = threadIdx.x;
  const int lane = tid & 63, wid = tid >> 6;
  const int l15 = lane & 15, lh = lane >> 4;
  const int wm = wid >> 1, wn = wid & 1;
  const size_t m0 = (size_t)blockIdx.y * 128, n0 = (size_t)blockIdx.x * 128;
  f32x4 acc[4][4];
  #pragma unroll
  for (int i=0;i<4;++i)
    #pragma unroll
    for (int j=0;j<4;++j) acc[i][j] = (f32x4){0.f,0.f,0.f,0.f};

  const int srow8 = lane >> 3;        // 0..7 row-within-8
  const int scol  = (lane & 7) * 8;   // 0..56 elem col

  for (int k0 = 0; k0 < K; k0 += 64) {
    __syncthreads();                  // all waves done reading previous tile
    #pragma unroll
    for (int i = 0; i < 4; ++i) {
      int r = wid*32 + i*8;           // wave-uniform LDS row base
      int ar = (int)m0 + r + srow8; if (ar >= M) ar = M - 1;
      gload16(A  + (size_t)ar*K + k0 + scol,                    &As[r*64]);
      gload16(Bt + (n0 + (size_t)(r + srow8))*K + k0 + scol,    &Bs[r*64]);
    }
    __syncthreads();                  // drains vmcnt(0): LDS tile ready
    #pragma unroll
    for (int kk = 0; kk < 2; ++kk) {
      bf16x8 af[4], bfr[4];
      #pragma unroll
      for (int i=0;i<4;++i){
        af[i]  = *(const bf16x8*)&As[(wm*64 + i*16 + l15)*64 + kk*32 + 8*lh];
        bfr[i] = *(const bf16x8*)&Bs[(wn*64 + i*16 + l15)*64 + kk*32 + 8*lh];
      }
      #pragma unroll
      for (int mi=0;mi<4;++mi)
        #pragma unroll
        for (int ni=0;ni<4;++ni)
          MFMA16(af[mi], bfr[ni], acc[mi][ni]);
    }
  }
  #pragma unroll
  for (int mi=0;mi<4;++mi){
    #pragma unroll
    for (int r=0;r<4;++r){
      size_t row = m0 + wm*64 + mi*16 + 4*lh + r;
      if (row < (size_t)M) {
        #pragma unroll
        for (int ni=0;ni<4;++ni){
          size_t col = n0 + wn*64 + ni*16 + l15;
          float v = acc[mi][ni][r];
          if (MODE==0) ((bf16*)outp)[row*(size_t)N + col] = (bf16)v;
          else if (MODE==1) ((float*)outp)[row*(size_t)N + col] = v + bias[col] + resid[row*(size_t)N + col];
          else { v += bias[col];
                 ((bf16*)outp)[row*(size_t)N + col] =
                     (bf16)(0.5f*v*(1.0f + erff(v*0.70710678f))); }
        }
      }
    }
  }
}

// ---- V rearrange for SA: vt[bh][d][s] = qkv[b*2048+s][2048 + h*64 + d] ----
__global__ __launch_bounds__(256) void vtsa_kernel(const bf16* __restrict__ qkv, bf16* __restrict__ vt)
{
  __shared__ bf16 t[32][33];
  const int b = blockIdx.z >> 4, h = blockIdx.z & 15;
  const int s0 = blockIdx.x*32, d0 = blockIdx.y*32;
  const int tx = threadIdx.x & 31, ty = threadIdx.x >> 5;
  #pragma unroll
  for (int i = ty; i < 32; i += 8)
    t[i][tx] = qkv[(size_t)(b*2048 + s0+i)*3072 + 2048 + h*64 + d0 + tx];
  __syncthreads();
  #pragma unroll
  for (int i = ty; i < 32; i += 8)
    vt[((size_t)blockIdx.z*64 + d0+i)*2048 + s0 + tx] = t[tx][i];
}

// ---- CA KV rearrange (pad 77 -> 128, zero fill) ----
__global__ __launch_bounds__(256) void kvca_re(const bf16* __restrict__ kvca,
    bf16* __restrict__ kpad, bf16* __restrict__ vtca)
{
  int idx = blockIdx.x*256 + threadIdx.x;           // over 2*16*128*64 = 262144
  if (idx >= 2*16*128*64) return;
  int d = idx & 63, s = (idx>>6) & 127, h = (idx>>13) & 15, b = idx>>17;
  bf16 kv = (bf16)0.f, vv = (bf16)0.f;
  if (s < 77) {
    kv = kvca[(size_t)(b*77+s)*2048 + h*64 + d];
    vv = kvca[(size_t)(b*77+s)*2048 + 1024 + h*64 + d];
  }
  kpad[idx] = kv;                                   // [b][h][s][d]
  vtca[(((size_t)(b*16+h)*64 + d)<<7) + s] = vv;    // [b][h][d][s], stride 128
}

// ---- Flash attention v2 ----
// Paired q-tiles (bx and nt-1-bx) for uniform causal load; 4 waves x 16 rows,
// KVBLK=64, double-buffered K/V LDS with async reg-staged prefetch, XOR 16B-slot
// swizzle on K/V (write+read), single barrier per kv-iter.
template<int CAUSAL>
__global__ __launch_bounds__(256) void flash2(
    const bf16* __restrict__ qb, long q_bstride, long qstride,
    const bf16* __restrict__ kb0, long k_bstride, long k_hstride, long kstride,
    const bf16* __restrict__ vtb, long vt_bhstride, long vtstride,
    bf16* __restrict__ out, int skv, int nt)
{
  __shared__ __align__(16) bf16 Ks[2][64*64];
  __shared__ __align__(16) bf16 Vs[2][64*64];
  __shared__ __align__(16) bf16 Ps[4][16*68];
  const int tid = threadIdx.x;
  const int w = tid >> 6, lane = tid & 63, l15 = lane & 15, lh = lane >> 4;
  const int bh = blockIdx.y, b = bh >> 4, h = bh & 15;
  const bf16* kbase = kb0 + (size_t)b*k_bstride + (size_t)h*k_hstride;
  const bf16* vbase = vtb + (size_t)bh*vt_bhstride;
  // staging geometry: chunk = tid + 256*i -> row = chunk>>3 (0..63), slot = chunk&7
  const int sr0 = tid >> 3, sslot = tid & 7;

  for (int half = 0; half < 2; ++half) {
    const int tile = (half == 0) ? (int)blockIdx.x : (nt - 1 - (int)blockIdx.x);
    const int q0 = tile * 64;
    const int nkb = CAUSAL ? (q0 >> 6) + 1 : ((skv + 63) >> 6);

    const bf16* qrow = qb + (size_t)b*q_bstride + (size_t)h*64
                          + (size_t)(q0 + w*16 + l15)*qstride;
    bf16x8 qf0 = *(const bf16x8*)(qrow + 8*lh);
    bf16x8 qf1 = *(const bf16x8*)(qrow + 32 + 8*lh);

    f32x4 o[4];
    #pragma unroll
    for (int i=0;i<4;++i) o[i] = (f32x4){0.f,0.f,0.f,0.f};
    float mr[4] = {-1e30f,-1e30f,-1e30f,-1e30f};
    float lr[4] = {0.f,0.f,0.f,0.f};

    // prologue prefetch kb=0
    bf16x8 kreg[2], vreg[2];
    #pragma unroll
    for (int i=0;i<2;++i){
      int r = sr0 + 32*i;
      kreg[i] = *(const bf16x8*)(kbase + (size_t)r*kstride + sslot*8);
      vreg[i] = *(const bf16x8*)(vbase + (size_t)r*vtstride + sslot*8);
    }

    for (int kb = 0; kb < nkb; ++kb) {
      const int buf = kb & 1;
      // stage prefetched regs into LDS (swizzled 16B slots)
      #pragma unroll
      for (int i=0;i<2;++i){
        int r = sr0 + 32*i;
        int ps = (sslot ^ (r & 7)) * 8;
        *(bf16x8*)&Ks[buf][r*64 + ps] = kreg[i];
        *(bf16x8*)&Vs[buf][r*64 + ps] = vreg[i];
      }
      __syncthreads();
      // async prefetch next kv-block (hidden under compute)
      if (kb + 1 < nkb) {
        #pragma unroll
        for (int i=0;i<2;++i){
          int r = sr0 + 32*i;
          kreg[i] = *(const bf16x8*)(kbase + (size_t)((kb+1)*64 + r)*kstride + sslot*8);
          vreg[i] = *(const bf16x8*)(vbase + (size_t)r*vtstride + (kb+1)*64 + sslot*8);
        }
      }
      // QK^T
      f32x4 sf[4];
      #pragma unroll
      for (int ni = 0; ni < 4; ++ni) {
        int kr = ni*16 + l15;
        bf16x8 kf0 = *(const bf16x8*)&Ks[buf][kr*64 + (((lh  ) ^ (kr&7))<<3)];
        bf16x8 kf1 = *(const bf16x8*)&Ks[buf][kr*64 + (((lh+4) ^ (kr&7))<<3)];
        f32x4 z = (f32x4){0.f,0.f,0.f,0.f};
        MFMA16(qf0, kf0, z);
        MFMA16(qf1, kf1, z);
        sf[ni] = z;
      }
      // mask + online softmax
      float mnew[4];
      #pragma unroll
      for (int r=0;r<4;++r) mnew[r] = mr[r];
      #pragma unroll
      for (int ni=0;ni<4;++ni){
        int col = kb*64 + ni*16 + l15;
        #pragma unroll
        for (int r=0;r<4;++r){
          int rowg = q0 + w*16 + 4*lh + r;
          float v = sf[ni][r] * 0.125f;
          if (col >= skv || (CAUSAL && col > rowg)) v = -1e30f;
          sf[ni][r] = v;
          mnew[r] = fmaxf(mnew[r], v);
        }
      }
      #pragma unroll
      for (int off=1; off<16; off<<=1)
        #pragma unroll
        for (int r=0;r<4;++r) mnew[r] = fmaxf(mnew[r], __shfl_xor(mnew[r], off));
      float alpha[4], rsum[4];
      #pragma unroll
      for (int r=0;r<4;++r){ alpha[r] = __expf(mr[r]-mnew[r]); mr[r] = mnew[r]; rsum[r] = 0.f; }
      #pragma unroll
      for (int ni=0;ni<4;++ni){
        #pragma unroll
        for (int r=0;r<4;++r){
          float p = __expf(sf[ni][r] - mnew[r]);
          rsum[r] += p;
          Ps[w][(4*lh + r)*68 + ni*16 + l15] = (bf16)p;   // natural [q][kv]
        }
      }
      #pragma unroll
      for (int off=1; off<16; off<<=1)
        #pragma unroll
        for (int r=0;r<4;++r) rsum[r] += __shfl_xor(rsum[r], off);
      #pragma unroll
      for (int r=0;r<4;++r) lr[r] = lr[r]*alpha[r] + rsum[r];
      #pragma unroll
      for (int nd=0;nd<4;++nd)
        #pragma unroll
        for (int r=0;r<4;++r) o[nd][r] *= alpha[r];
      // P @ V
      bf16x8 pa0 = *(const bf16x8*)&Ps[w][l15*68 + 8*lh];
      bf16x8 pa1 = *(const bf16x8*)&Ps[w][l15*68 + 32 + 8*lh];
      #pragma unroll
      for (int nd=0;nd<4;++nd){
        int vr = nd*16 + l15;
        bf16x8 vf0 = *(const bf16x8*)&Vs[buf][vr*64 + (((lh  ) ^ (vr&7))<<3)];
        bf16x8 vf1 = *(const bf16x8*)&Vs[buf][vr*64 + (((lh+4) ^ (vr&7))<<3)];
        MFMA16(pa0, vf0, o[nd]);
        MFMA16(pa1, vf1, o[nd]);
      }
    }
    __syncthreads();   // pass done before next half re-stages LDS
    #pragma unroll
    for (int nd=0;nd<4;++nd)
      #pragma unroll
      for (int r=0;r<4;++r){
        int rowg = q0 + w*16 + 4*lh + r;
        out[(size_t)(b*2048 + rowg)*1024 + h*64 + nd*16 + l15] =
            (bf16)(o[nd][r] / lr[r]);
      }
  }
}

// ---- host ----
struct Bump { char* base; size_t off;
  void* get(size_t bytes){ void* p = base + off; off += (bytes + 255) & ~(size_t)255; return p; } };

extern "C" void kernel_launch(void* const* d_in, const int* in_sizes, int n_in,
                              void* d_out, int out_size, void* d_ws, size_t ws_size,
                              hipStream_t stream)
{
  const float* x        = (const float*)d_in[0];
  const float* cond     = (const float*)d_in[1];
  const float* Wqkv     = (const float*)d_in[2];
  const float* Wproj_sa = (const float*)d_in[3];
  const float* bproj_sa = (const float*)d_in[4];
  const float* g1       = (const float*)d_in[5];
  const float* b1       = (const float*)d_in[6];
  const float* Wq_ca    = (const float*)d_in[7];
  const float* Wkv_ca   = (const float*)d_in[8];
  const float* Wproj_ca = (const float*)d_in[9];
  const float* bproj_ca = (const float*)d_in[10];
  const float* g2       = (const float*)d_in[11];
  const float* b2       = (const float*)d_in[12];
  const float* Wff1     = (const float*)d_in[13];
  const float* bff1     = (const float*)d_in[14];
  const float* Wff2     = (const float*)d_in[15];
  const float* bff2     = (const float*)d_in[16];
  const float* g3       = (const float*)d_in[17];
  const float* b3       = (const float*)d_in[18];

  Bump bump{(char*)d_ws, 0};
  bf16* wqkvT    = (bf16*)bump.get((size_t)3072*1024*2);
  bf16* wprojSaT = (bf16*)bump.get((size_t)1024*1024*2);
  bf16* wqCaT    = (bf16*)bump.get((size_t)1024*1024*2);
  bf16* wkvCaT   = (bf16*)bump.get((size_t)2048*768*2);
  bf16* wprojCaT = (bf16*)bump.get((size_t)1024*1024*2);
  bf16* wff1T    = (bf16*)bump.get((size_t)4096*1024*2);
  bf16* wff2T    = (bf16*)bump.get((size_t)1024*4096*2);
  bf16* condb    = (bf16*)bump.get((size_t)154*768*2);
  bf16* xn       = (bf16*)bump.get((size_t)4096*1024*2);
  bf16* qkv      = (bf16*)bump.get((size_t)4096*3072*2);   // 25165824 B
  bf16* vt_sa    = (bf16*)bump.get((size_t)2*16*64*2048*2);//  8388608 B (follows qkv)
  bf16* attn     = (bf16*)bump.get((size_t)4096*1024*2);
  bf16* kvca     = (bf16*)bump.get((size_t)154*2048*2);
  bf16* kpad     = (bf16*)bump.get((size_t)2*16*128*64*2);
  bf16* vtca     = (bf16*)bump.get((size_t)2*16*64*128*2);
  bf16* h1   = qkv;             // FF hidden: qkv+vt_sa dead by FF1
  bf16* qca  = vt_sa;           // CA query: vt_sa dead after SA flash
  float* x1  = (float*)d_out;   // residual stream lives in d_out

  tcast<<<dim3(96,32),  256, 0, stream>>>(Wqkv,     wqkvT,    1024, 3072);
  tcast<<<dim3(32,32),  256, 0, stream>>>(Wproj_sa, wprojSaT, 1024, 1024);
  tcast<<<dim3(32,32),  256, 0, stream>>>(Wq_ca,    wqCaT,    1024, 1024);
  tcast<<<dim3(64,24),  256, 0, stream>>>(Wkv_ca,   wkvCaT,    768, 2048);
  tcast<<<dim3(32,32),  256, 0, stream>>>(Wproj_ca, wprojCaT, 1024, 1024);
  tcast<<<dim3(128,32), 256, 0, stream>>>(Wff1,     wff1T,    1024, 4096);
  tcast<<<dim3(32,128), 256, 0, stream>>>(Wff2,     wff2T,    4096, 1024);
  cast_bf16<<<dim3(462), 256, 0, stream>>>(cond, condb, 118272);

  // self-attention
  ln_kernel<<<dim3(4096), 256, 0, stream>>>(x, g1, b1, xn);
  gemm_bt<0><<<dim3(24,32), 256, 0, stream>>>(xn, wqkvT, nullptr, nullptr, qkv, 4096, 3072, 1024);
  vtsa_kernel<<<dim3(64,2,32), 256, 0, stream>>>(qkv, vt_sa);
  flash2<1><<<dim3(16,32), 256, 0, stream>>>(
      qkv,        (long)2048*3072, 3072,
      qkv + 1024, (long)2048*3072, 64, 3072,
      vt_sa,      (long)64*2048, 2048,
      attn, 2048, 32);
  gemm_bt<1><<<dim3(8,32), 256, 0, stream>>>(attn, wprojSaT, bproj_sa, x, x1, 4096, 1024, 1024);

  // cross-attention
  ln_kernel<<<dim3(4096), 256, 0, stream>>>(x1, g2, b2, xn);
  gemm_bt<0><<<dim3(8,32), 256, 0, stream>>>(xn, wqCaT, nullptr, nullptr, qca, 4096, 1024, 1024);
  gemm_bt<0><<<dim3(16,2), 256, 0, stream>>>(condb, wkvCaT, nullptr, nullptr, kvca, 154, 2048, 768);
  kvca_re<<<dim3(1024), 256, 0, stream>>>(kvca, kpad, vtca);
  flash2<0><<<dim3(16,32), 256, 0, stream>>>(
      qca,  (long)2048*1024, 1024,
      kpad, (long)16*128*64, (long)128*64, 64,
      vtca, (long)64*128, 128,
      attn, 77, 32);
  gemm_bt<1><<<dim3(8,32), 256, 0, stream>>>(attn, wprojCaT, bproj_ca, x1, x1, 4096, 1024, 1024);

  // FFN
  ln_kernel<<<dim3(4096), 256, 0, stream>>>(x1, g3, b3, xn);
  gemm_bt<2><<<dim3(32,32), 256, 0, stream>>>(xn, wff1T, bff1, nullptr, h1, 4096, 4096, 1024);
  gemm_bt<1><<<dim3(8,32), 256, 0, stream>>>(h1, wff2T, bff2, x1, d_out, 4096, 1024, 4096);

  (void)in_sizes; (void)n_in; (void)out_size; (void)ws_size;
}

// Round 5
// 399.265 us; speedup vs baseline: 1.3741x; 1.2210x over previous
//
#include <hip/hip_runtime.h>

using bf16   = __bf16;
using bf16x8 = __attribute__((ext_vector_type(8))) bf16;
using f32x4  = __attribute__((ext_vector_type(4))) float;

#define DEV static __device__ __forceinline__

DEV void MFMA16(bf16x8 a, bf16x8 b, f32x4& c){
  c = __builtin_amdgcn_mfma_f32_16x16x32_bf16(a, b, c, 0, 0, 0);
}

// async global->LDS DMA, 16B per lane; lds dest is wave-uniform base + lane*16
DEV void gload16(const bf16* g, bf16* lds){
  __builtin_amdgcn_global_load_lds(
      (const __attribute__((address_space(1))) void*)g,
      (__attribute__((address_space(3))) void*)lds, 16, 0, 0);
}

// ---- transpose-cast: out[c][r] = bf16(in[r][c]); R,C multiples of 32 ----
__global__ __launch_bounds__(256) void tcast(const float* __restrict__ in, bf16* __restrict__ out,
                                             int R, int C)
{
  __shared__ float t[32][33];
  const int c0 = blockIdx.x*32, r0 = blockIdx.y*32;
  const int tx = threadIdx.x & 31, ty = threadIdx.x >> 5;
  #pragma unroll
  for (int i = ty; i < 32; i += 8) t[i][tx] = in[(size_t)(r0+i)*C + c0+tx];
  __syncthreads();
  #pragma unroll
  for (int i = ty; i < 32; i += 8) out[(size_t)(c0+i)*R + r0+tx] = (bf16)t[tx][i];
}

__global__ void cast_bf16(const float* __restrict__ in, bf16* __restrict__ out, int n){
  int i = blockIdx.x*256 + threadIdx.x;
  if (i < n) out[i] = (bf16)in[i];
}

// ---- LayerNorm: one block per row of 1024, fp32 in -> bf16 out ----
__global__ __launch_bounds__(256) void ln_kernel(const float* __restrict__ x,
    const float* __restrict__ gw, const float* __restrict__ bw, bf16* __restrict__ y)
{
  const int row = blockIdx.x;
  const float4 v = ((const float4*)(x + (size_t)row*1024))[threadIdx.x];
  float s  = v.x+v.y+v.z+v.w;
  float s2 = v.x*v.x+v.y*v.y+v.z*v.z+v.w*v.w;
  #pragma unroll
  for (int off=32; off>=1; off>>=1){ s += __shfl_down(s,off); s2 += __shfl_down(s2,off); }
  __shared__ float red[2][4];
  const int wid = threadIdx.x>>6, lane = threadIdx.x&63;
  if (lane==0){ red[0][wid]=s; red[1][wid]=s2; }
  __syncthreads();
  s  = red[0][0]+red[0][1]+red[0][2]+red[0][3];
  s2 = red[1][0]+red[1][1]+red[1][2]+red[1][3];
  const float m  = s*(1.f/1024.f);
  const float rs = rsqrtf(s2*(1.f/1024.f) - m*m + 1e-5f);
  const float4 gv = ((const float4*)gw)[threadIdx.x];
  const float4 bv = ((const float4*)bw)[threadIdx.x];
  bf16* yr = y + (size_t)row*1024 + threadIdx.x*4;
  yr[0] = (bf16)((v.x-m)*rs*gv.x + bv.x);
  yr[1] = (bf16)((v.y-m)*rs*gv.y + bv.y);
  yr[2] = (bf16)((v.z-m)*rs*gv.z + bv.z);
  yr[3] = (bf16)((v.w-m)*rs*gv.w + bv.w);
}

// ---- GEMM: out = epilogue(A[M][K] @ Bt[N][K]^T); 128x128 tile, BK=64 ----
// Pipelined 2-phase double-buffer: STAGE(t+1) issued BEFORE compute(t) so
// global_load_lds latency hides under the 32 MFMAs; one __syncthreads per
// K-step (drains vmcnt+lgkmcnt, covers both buffers). Both-sides LDS swizzle:
// global source column pre-swizzled gslot=(lane&7)^(lane>>3) (gload_lds writes
// LDS linearly), fragments read slot (kk*4+lh)^(row&7) -> 2-way conflicts only.
// XCD-aware bijective block swizzle (all grids here have nwg%8==0).
template<int MODE>
__global__ __launch_bounds__(256) void gemm_bt(
    const bf16* __restrict__ A, const bf16* __restrict__ Bt,
    const float* __restrict__ bias, const float* resid,
    void* outp, int M, int N, int K)
{
  __shared__ __align__(16) bf16 As[2][128*64];
  __shared__ __align__(16) bf16 Bs[2][128*64];
  const int tid = threadIdx.x;
  const int lane = tid & 63, wid = tid >> 6;
  const int l15 = lane & 15, lh = lane >> 4;
  const int wm = wid >> 1, wn = wid & 1;

  const int nwg = gridDim.x * gridDim.y;
  const int lin = blockIdx.y * gridDim.x + blockIdx.x;
  const int wg  = (lin & 7) * (nwg >> 3) + (lin >> 3);   // XCD gets contiguous chunk
  const size_t m0 = (size_t)(wg / gridDim.x) * 128;
  const size_t n0 = (size_t)(wg % gridDim.x) * 128;

  f32x4 acc[4][4];
  #pragma unroll
  for (int i=0;i<4;++i)
    #pragma unroll
    for (int j=0;j<4;++j) acc[i][j] = (f32x4){0.f,0.f,0.f,0.f};

  const int srow8 = lane >> 3;                 // row within 8-row stage group
  const int scol  = ((lane & 7) ^ srow8) * 8;  // pre-swizzled global column

  const int NT = K >> 6;

  // prologue: stage tile 0 into buf 0
  #pragma unroll
  for (int i = 0; i < 4; ++i) {
    int r = wid*32 + i*8;
    int ar = (int)m0 + r + srow8; if (ar >= M) ar = M - 1;
    gload16(A  + (size_t)ar*K + scol,                 &As[0][r*64]);
    gload16(Bt + (n0 + (size_t)(r + srow8))*K + scol, &Bs[0][r*64]);
  }
  __syncthreads();

  for (int t = 0; t < NT; ++t) {
    const int cur = t & 1;
    if (t + 1 < NT) {
      const int k0 = (t+1) << 6;
      #pragma unroll
      for (int i = 0; i < 4; ++i) {
        int r = wid*32 + i*8;
        int ar = (int)m0 + r + srow8; if (ar >= M) ar = M - 1;
        gload16(A  + (size_t)ar*K + k0 + scol,                 &As[cur^1][r*64]);
        gload16(Bt + (n0 + (size_t)(r + srow8))*K + k0 + scol, &Bs[cur^1][r*64]);
      }
    }
    #pragma unroll
    for (int kk = 0; kk < 2; ++kk) {
      bf16x8 af[4], bfr[4];
      #pragma unroll
      for (int i=0;i<4;++i){
        const int arow = wm*64 + i*16 + l15;
        const int brow = wn*64 + i*16 + l15;
        af[i]  = *(const bf16x8*)&As[cur][arow*64 + (((kk*4+lh) ^ (arow&7))<<3)];
        bfr[i] = *(const bf16x8*)&Bs[cur][brow*64 + (((kk*4+lh) ^ (brow&7))<<3)];
      }
      #pragma unroll
      for (int mi=0;mi<4;++mi)
        #pragma unroll
        for (int ni=0;ni<4;++ni)
          MFMA16(af[mi], bfr[ni], acc[mi][ni]);
    }
    __syncthreads();   // drains stage(t+1) vmcnt + all lgkm; both buffers safe
  }

  #pragma unroll
  for (int mi=0;mi<4;++mi){
    #pragma unroll
    for (int r=0;r<4;++r){
      size_t row = m0 + wm*64 + mi*16 + 4*lh + r;
      if (row < (size_t)M) {
        #pragma unroll
        for (int ni=0;ni<4;++ni){
          size_t col = n0 + wn*64 + ni*16 + l15;
          float v = acc[mi][ni][r];
          if (MODE==0) ((bf16*)outp)[row*(size_t)N + col] = (bf16)v;
          else if (MODE==1) ((float*)outp)[row*(size_t)N + col] = v + bias[col] + resid[row*(size_t)N + col];
          else { v += bias[col];
                 ((bf16*)outp)[row*(size_t)N + col] =
                     (bf16)(0.5f*v*(1.0f + erff(v*0.70710678f))); }
        }
      }
    }
  }
}

// ---- V rearrange for SA: vt[bh][d][s] = qkv[b*2048+s][2048 + h*64 + d] ----
__global__ __launch_bounds__(256) void vtsa_kernel(const bf16* __restrict__ qkv, bf16* __restrict__ vt)
{
  __shared__ bf16 t[32][33];
  const int b = blockIdx.z >> 4, h = blockIdx.z & 15;
  const int s0 = blockIdx.x*32, d0 = blockIdx.y*32;
  const int tx = threadIdx.x & 31, ty = threadIdx.x >> 5;
  #pragma unroll
  for (int i = ty; i < 32; i += 8)
    t[i][tx] = qkv[(size_t)(b*2048 + s0+i)*3072 + 2048 + h*64 + d0 + tx];
  __syncthreads();
  #pragma unroll
  for (int i = ty; i < 32; i += 8)
    vt[((size_t)blockIdx.z*64 + d0+i)*2048 + s0 + tx] = t[tx][i];
}

// ---- CA KV rearrange (pad 77 -> 128, zero fill) ----
__global__ __launch_bounds__(256) void kvca_re(const bf16* __restrict__ kvca,
    bf16* __restrict__ kpad, bf16* __restrict__ vtca)
{
  int idx = blockIdx.x*256 + threadIdx.x;           // over 2*16*128*64 = 262144
  if (idx >= 2*16*128*64) return;
  int d = idx & 63, s = (idx>>6) & 127, h = (idx>>13) & 15, b = idx>>17;
  bf16 kv = (bf16)0.f, vv = (bf16)0.f;
  if (s < 77) {
    kv = kvca[(size_t)(b*77+s)*2048 + h*64 + d];
    vv = kvca[(size_t)(b*77+s)*2048 + 1024 + h*64 + d];
  }
  kpad[idx] = kv;                                   // [b][h][s][d]
  vtca[(((size_t)(b*16+h)*64 + d)<<7) + s] = vv;    // [b][h][d][s], stride 128
}

// ---- Flash attention v2 ----
// Paired q-tiles (bx and nt-1-bx) for uniform causal load; 4 waves x 16 rows,
// KVBLK=64, double-buffered K/V LDS with reg-staged prefetch, XOR 16B-slot
// swizzle on K/V (write+read), single barrier per kv-iter.
template<int CAUSAL>
__global__ __launch_bounds__(256) void flash2(
    const bf16* __restrict__ qb, long q_bstride, long qstride,
    const bf16* __restrict__ kb0, long k_bstride, long k_hstride, long kstride,
    const bf16* __restrict__ vtb, long vt_bhstride, long vtstride,
    bf16* __restrict__ out, int skv, int nt)
{
  __shared__ __align__(16) bf16 Ks[2][64*64];
  __shared__ __align__(16) bf16 Vs[2][64*64];
  __shared__ __align__(16) bf16 Ps[4][16*68];
  const int tid = threadIdx.x;
  const int w = tid >> 6, lane = tid & 63, l15 = lane & 15, lh = lane >> 4;
  const int bh = blockIdx.y, b = bh >> 4, h = bh & 15;
  const bf16* kbase = kb0 + (size_t)b*k_bstride + (size_t)h*k_hstride;
  const bf16* vbase = vtb + (size_t)bh*vt_bhstride;
  const int sr0 = tid >> 3, sslot = tid & 7;

  for (int half = 0; half < 2; ++half) {
    const int tile = (half == 0) ? (int)blockIdx.x : (nt - 1 - (int)blockIdx.x);
    const int q0 = tile * 64;
    const int nkb = CAUSAL ? (q0 >> 6) + 1 : ((skv + 63) >> 6);

    const bf16* qrow = qb + (size_t)b*q_bstride + (size_t)h*64
                          + (size_t)(q0 + w*16 + l15)*qstride;
    bf16x8 qf0 = *(const bf16x8*)(qrow + 8*lh);
    bf16x8 qf1 = *(const bf16x8*)(qrow + 32 + 8*lh);

    f32x4 o[4];
    #pragma unroll
    for (int i=0;i<4;++i) o[i] = (f32x4){0.f,0.f,0.f,0.f};
    float mr[4] = {-1e30f,-1e30f,-1e30f,-1e30f};
    float lr[4] = {0.f,0.f,0.f,0.f};

    bf16x8 kreg[2], vreg[2];
    #pragma unroll
    for (int i=0;i<2;++i){
      int r = sr0 + 32*i;
      kreg[i] = *(const bf16x8*)(kbase + (size_t)r*kstride + sslot*8);
      vreg[i] = *(const bf16x8*)(vbase + (size_t)r*vtstride + sslot*8);
    }

    for (int kb = 0; kb < nkb; ++kb) {
      const int buf = kb & 1;
      #pragma unroll
      for (int i=0;i<2;++i){
        int r = sr0 + 32*i;
        int ps = (sslot ^ (r & 7)) * 8;
        *(bf16x8*)&Ks[buf][r*64 + ps] = kreg[i];
        *(bf16x8*)&Vs[buf][r*64 + ps] = vreg[i];
      }
      __syncthreads();
      if (kb + 1 < nkb) {
        #pragma unroll
        for (int i=0;i<2;++i){
          int r = sr0 + 32*i;
          kreg[i] = *(const bf16x8*)(kbase + (size_t)((kb+1)*64 + r)*kstride + sslot*8);
          vreg[i] = *(const bf16x8*)(vbase + (size_t)r*vtstride + (kb+1)*64 + sslot*8);
        }
      }
      f32x4 sf[4];
      #pragma unroll
      for (int ni = 0; ni < 4; ++ni) {
        int kr = ni*16 + l15;
        bf16x8 kf0 = *(const bf16x8*)&Ks[buf][kr*64 + (((lh  ) ^ (kr&7))<<3)];
        bf16x8 kf1 = *(const bf16x8*)&Ks[buf][kr*64 + (((lh+4) ^ (kr&7))<<3)];
        f32x4 z = (f32x4){0.f,0.f,0.f,0.f};
        MFMA16(qf0, kf0, z);
        MFMA16(qf1, kf1, z);
        sf[ni] = z;
      }
      float mnew[4];
      #pragma unroll
      for (int r=0;r<4;++r) mnew[r] = mr[r];
      #pragma unroll
      for (int ni=0;ni<4;++ni){
        int col = kb*64 + ni*16 + l15;
        #pragma unroll
        for (int r=0;r<4;++r){
          int rowg = q0 + w*16 + 4*lh + r;
          float v = sf[ni][r] * 0.125f;
          if (col >= skv || (CAUSAL && col > rowg)) v = -1e30f;
          sf[ni][r] = v;
          mnew[r] = fmaxf(mnew[r], v);
        }
      }
      #pragma unroll
      for (int off=1; off<16; off<<=1)
        #pragma unroll
        for (int r=0;r<4;++r) mnew[r] = fmaxf(mnew[r], __shfl_xor(mnew[r], off));
      float alpha[4], rsum[4];
      #pragma unroll
      for (int r=0;r<4;++r){ alpha[r] = __expf(mr[r]-mnew[r]); mr[r] = mnew[r]; rsum[r] = 0.f; }
      #pragma unroll
      for (int ni=0;ni<4;++ni){
        #pragma unroll
        for (int r=0;r<4;++r){
          float p = __expf(sf[ni][r] - mnew[r]);
          rsum[r] += p;
          Ps[w][(4*lh + r)*68 + ni*16 + l15] = (bf16)p;
        }
      }
      #pragma unroll
      for (int off=1; off<16; off<<=1)
        #pragma unroll
        for (int r=0;r<4;++r) rsum[r] += __shfl_xor(rsum[r], off);
      #pragma unroll
      for (int r=0;r<4;++r) lr[r] = lr[r]*alpha[r] + rsum[r];
      #pragma unroll
      for (int nd=0;nd<4;++nd)
        #pragma unroll
        for (int r=0;r<4;++r) o[nd][r] *= alpha[r];
      bf16x8 pa0 = *(const bf16x8*)&Ps[w][l15*68 + 8*lh];
      bf16x8 pa1 = *(const bf16x8*)&Ps[w][l15*68 + 32 + 8*lh];
      #pragma unroll
      for (int nd=0;nd<4;++nd){
        int vr = nd*16 + l15;
        bf16x8 vf0 = *(const bf16x8*)&Vs[buf][vr*64 + (((lh  ) ^ (vr&7))<<3)];
        bf16x8 vf1 = *(const bf16x8*)&Vs[buf][vr*64 + (((lh+4) ^ (vr&7))<<3)];
        MFMA16(pa0, vf0, o[nd]);
        MFMA16(pa1, vf1, o[nd]);
      }
    }
    __syncthreads();
    #pragma unroll
    for (int nd=0;nd<4;++nd)
      #pragma unroll
      for (int r=0;r<4;++r){
        int rowg = q0 + w*16 + 4*lh + r;
        out[(size_t)(b*2048 + rowg)*1024 + h*64 + nd*16 + l15] =
            (bf16)(o[nd][r] / lr[r]);
      }
  }
}

// ---- host ----
struct Bump { char* base; size_t off;
  void* get(size_t bytes){ void* p = base + off; off += (bytes + 255) & ~(size_t)255; return p; } };

extern "C" void kernel_launch(void* const* d_in, const int* in_sizes, int n_in,
                              void* d_out, int out_size, void* d_ws, size_t ws_size,
                              hipStream_t stream)
{
  const float* x        = (const float*)d_in[0];
  const float* cond     = (const float*)d_in[1];
  const float* Wqkv     = (const float*)d_in[2];
  const float* Wproj_sa = (const float*)d_in[3];
  const float* bproj_sa = (const float*)d_in[4];
  const float* g1       = (const float*)d_in[5];
  const float* b1       = (const float*)d_in[6];
  const float* Wq_ca    = (const float*)d_in[7];
  const float* Wkv_ca   = (const float*)d_in[8];
  const float* Wproj_ca = (const float*)d_in[9];
  const float* bproj_ca = (const float*)d_in[10];
  const float* g2       = (const float*)d_in[11];
  const float* b2       = (const float*)d_in[12];
  const float* Wff1     = (const float*)d_in[13];
  const float* bff1     = (const float*)d_in[14];
  const float* Wff2     = (const float*)d_in[15];
  const float* bff2     = (const float*)d_in[16];
  const float* g3       = (const float*)d_in[17];
  const float* b3       = (const float*)d_in[18];

  Bump bump{(char*)d_ws, 0};
  bf16* wqkvT    = (bf16*)bump.get((size_t)3072*1024*2);
  bf16* wprojSaT = (bf16*)bump.get((size_t)1024*1024*2);
  bf16* wqCaT    = (bf16*)bump.get((size_t)1024*1024*2);
  bf16* wkvCaT   = (bf16*)bump.get((size_t)2048*768*2);
  bf16* wprojCaT = (bf16*)bump.get((size_t)1024*1024*2);
  bf16* wff1T    = (bf16*)bump.get((size_t)4096*1024*2);
  bf16* wff2T    = (bf16*)bump.get((size_t)1024*4096*2);
  bf16* condb    = (bf16*)bump.get((size_t)154*768*2);
  bf16* xn       = (bf16*)bump.get((size_t)4096*1024*2);
  bf16* qkv      = (bf16*)bump.get((size_t)4096*3072*2);   // 25165824 B
  bf16* vt_sa    = (bf16*)bump.get((size_t)2*16*64*2048*2);//  8388608 B (follows qkv)
  bf16* attn     = (bf16*)bump.get((size_t)4096*1024*2);
  bf16* kvca     = (bf16*)bump.get((size_t)154*2048*2);
  bf16* kpad     = (bf16*)bump.get((size_t)2*16*128*64*2);
  bf16* vtca     = (bf16*)bump.get((size_t)2*16*64*128*2);
  bf16* h1   = qkv;             // FF hidden: qkv+vt_sa dead by FF1
  bf16* qca  = vt_sa;           // CA query: vt_sa dead after SA flash
  float* x1  = (float*)d_out;   // residual stream lives in d_out

  tcast<<<dim3(96,32),  256, 0, stream>>>(Wqkv,     wqkvT,    1024, 3072);
  tcast<<<dim3(32,32),  256, 0, stream>>>(Wproj_sa, wprojSaT, 1024, 1024);
  tcast<<<dim3(32,32),  256, 0, stream>>>(Wq_ca,    wqCaT,    1024, 1024);
  tcast<<<dim3(64,24),  256, 0, stream>>>(Wkv_ca,   wkvCaT,    768, 2048);
  tcast<<<dim3(32,32),  256, 0, stream>>>(Wproj_ca, wprojCaT, 1024, 1024);
  tcast<<<dim3(128,32), 256, 0, stream>>>(Wff1,     wff1T,    1024, 4096);
  tcast<<<dim3(32,128), 256, 0, stream>>>(Wff2,     wff2T,    4096, 1024);
  cast_bf16<<<dim3(462), 256, 0, stream>>>(cond, condb, 118272);

  // self-attention
  ln_kernel<<<dim3(4096), 256, 0, stream>>>(x, g1, b1, xn);
  gemm_bt<0><<<dim3(24,32), 256, 0, stream>>>(xn, wqkvT, nullptr, nullptr, qkv, 4096, 3072, 1024);
  vtsa_kernel<<<dim3(64,2,32), 256, 0, stream>>>(qkv, vt_sa);
  flash2<1><<<dim3(16,32), 256, 0, stream>>>(
      qkv,        (long)2048*3072, 3072,
      qkv + 1024, (long)2048*3072, 64, 3072,
      vt_sa,      (long)64*2048, 2048,
      attn, 2048, 32);
  gemm_bt<1><<<dim3(8,32), 256, 0, stream>>>(attn, wprojSaT, bproj_sa, x, x1, 4096, 1024, 1024);

  // cross-attention
  ln_kernel<<<dim3(4096), 256, 0, stream>>>(x1, g2, b2, xn);
  gemm_bt<0><<<dim3(8,32), 256, 0, stream>>>(xn, wqCaT, nullptr, nullptr, qca, 4096, 1024, 1024);
  gemm_bt<0><<<dim3(16,2), 256, 0, stream>>>(condb, wkvCaT, nullptr, nullptr, kvca, 154, 2048, 768);
  kvca_re<<<dim3(1024), 256, 0, stream>>>(kvca, kpad, vtca);
  flash2<0><<<dim3(16,32), 256, 0, stream>>>(
      qca,  (long)2048*1024, 1024,
      kpad, (long)16*128*64, (long)128*64, 64,
      vtca, (long)64*128, 128,
      attn, 77, 32);
  gemm_bt<1><<<dim3(8,32), 256, 0, stream>>>(attn, wprojCaT, bproj_ca, x1, x1, 4096, 1024, 1024);

  // FFN
  ln_kernel<<<dim3(4096), 256, 0, stream>>>(x1, g3, b3, xn);
  gemm_bt<2><<<dim3(32,32), 256, 0, stream>>>(xn, wff1T, bff1, nullptr, h1, 4096, 4096, 1024);
  gemm_bt<1><<<dim3(8,32), 256, 0, stream>>>(h1, wff2T, bff2, x1, d_out, 4096, 1024, 4096);

  (void)in_sizes; (void)n_in; (void)out_size; (void)ws_size;
}